// Round 1
// baseline (489.871 us; speedup 1.0000x reference)
//
#include <hip/hip_runtime.h>
#include <math.h>

#define BB 2
#define TT 512
#define CC 64
#define HH 64
#define KK 128            // 2C
#define JT 64             // j-tile per block

typedef __attribute__((ext_vector_type(8))) short short8;
typedef __attribute__((ext_vector_type(4))) float float4v;

__device__ inline unsigned short f2bf(float f) {
    unsigned int u = __float_as_uint(f);
    u = (u + 0x7FFFu + ((u >> 16) & 1u)) >> 16;   // RNE
    return (unsigned short)u;
}

// ---------------------------------------------------------------------------
// prep (+fused pack): blocks [0, BB*TT) : kp/qpb/v rows.
//                     blocks [BB*TT, BB*TT+32): pack W1p into MFMA-fragment
//                     order Wpt[((nt*4+kt)*64 + kg*16 + m)*8 + e]
//                         = bf16(W1[(2C + kt*32+kg*8+e)*C + nt*16+m])
// so wei_kernel's B loads are straight coalesced 16B/lane register loads.
// ---------------------------------------------------------------------------
__global__ __launch_bounds__(64) void prep_kernel(
    const float* __restrict__ x, const float* __restrict__ pos_emb,
    const float* __restrict__ W1, const float* __restrict__ b1,
    const float* __restrict__ Wv, const float* __restrict__ bv,
    float* __restrict__ kp, float* __restrict__ qpb, float* __restrict__ v,
    unsigned short* __restrict__ Wpt)
{
    if (blockIdx.x >= BB * TT) {
        int base = (blockIdx.x - BB * TT) * 256 + threadIdx.x;
#pragma unroll
        for (int q = 0; q < 4; ++q) {
            int o  = base + q * 64;          // 0..8191
            int e  = o & 7;
            int mm = (o >> 3) & 15;
            int kg = (o >> 7) & 3;
            int kt = (o >> 9) & 3;
            int nt = (o >> 11) & 3;
            int k = kt * 32 + kg * 8 + e;
            int c = nt * 16 + mm;
            Wpt[o] = f2bf(W1[(2 * CC + k) * CC + c]);
        }
        return;
    }

    const int row = blockIdx.x;          // b*T + t
    const int t = row & (TT - 1);
    const int c = threadIdx.x;           // 0..63
    __shared__ float xs[CC], x1s[CC];
    float xv = x[row * CC + c];
    xs[c] = xv;
    x1s[c] = xv + pos_emb[t * CC + c];
    __syncthreads();
    float ak = 0.f, aq = 0.f, av = 0.f;
#pragma unroll 8
    for (int k = 0; k < CC; ++k) {
        ak = fmaf(x1s[k], W1[k * CC + c], ak);
        aq = fmaf(x1s[k], W1[(CC + k) * CC + c], aq);
        av = fmaf(xs[k], Wv[k * HH + c], av);
    }
    kp[row * CC + c] = ak;
    qpb[row * CC + c] = aq + b1[c];
    v[row * HH + c] = av + bv[c];
}

// ---------------------------------------------------------------------------
// wei_kernel v3: B operand in registers (fragment-packed Wpt, L2-hot),
// A tile in 16 KB XOR-swizzled LDS. One barrier per block.
//   ds_read_b128 per lane: 4 (was 20); LDS 16 KB (was 34 KB) -> 8 blocks/CU.
// Epilogue operands prefetched pre-barrier.
// ---------------------------------------------------------------------------
__global__ __launch_bounds__(256, 8) void wei_kernel(
    const float* __restrict__ pd, const unsigned short* __restrict__ Wpt,
    const float* __restrict__ W2, const float* __restrict__ b2,
    const float* __restrict__ kp, const float* __restrict__ qpb,
    float* __restrict__ wei)
{
    const int i = blockIdx.y;
    const int b = blockIdx.z;
    const int j0 = blockIdx.x * JT;
    if (j0 > i) return;                  // uniform early exit (before barrier)

    __shared__ unsigned short Alds[JT * KK];     // 16384 B, XOR-swizzled rows

    const int tid  = threadIdx.x;
    const int wave = tid >> 6;
    const int lane = tid & 63;
    const int m    = lane & 15;
    const int kg   = lane >> 4;

    // ---- B fragments: 16 coalesced 16B/lane loads, no barrier dependency ----
    short8 bfrag[4][4];
#pragma unroll
    for (int nt = 0; nt < 4; ++nt)
#pragma unroll
        for (int kt = 0; kt < 4; ++kt)
            bfrag[nt][kt] = *(const short8*)&Wpt[((nt * 4 + kt) * 64 + lane) * 8];

    // ---- epilogue operand prefetch (L2-hot; latency hides under stage+MFMA) ----
    float w2v[4], qv[4], kv[4][4];
#pragma unroll
    for (int nt = 0; nt < 4; ++nt) {
        int c = nt * 16 + m;
        w2v[nt] = W2[c];
        qv[nt]  = qpb[((size_t)b * TT + i) * CC + c];
    }
#pragma unroll
    for (int r = 0; r < 4; ++r) {
        int j = j0 + wave * 16 + kg * 4 + r;
#pragma unroll
        for (int nt = 0; nt < 4; ++nt)
            kv[r][nt] = kp[((size_t)b * TT + j) * CC + nt * 16 + m];
    }
    const float b2v = b2[0];

    // ---- stage A: pd fp32 -> bf16, coalesced float4 reads, swizzled LDS ----
    {
        const float4* __restrict__ p4 =
            (const float4*)(pd + (((size_t)b * TT + i) * TT + j0) * KK);
#pragma unroll
        for (int it = 0; it < 8; ++it) {
            int f = it * 256 + tid;          // 0..2047 float4
            float4 val = p4[f];
            int j  = f >> 5;                 // 32 float4 per row
            int kq = f & 31;
            uint2 u;
            u.x = (unsigned)f2bf(val.x) | ((unsigned)f2bf(val.y) << 16);
            u.y = (unsigned)f2bf(val.z) | ((unsigned)f2bf(val.w) << 16);
            *(uint2*)&Alds[j * KK + ((kq * 4) ^ ((j & 7) << 3))] = u;
        }
    }
    __syncthreads();

    // ---- MFMA: 4 ds_read_b128 + 16 MFMA per lane ----
    float4v acc[4] = {{0.f,0.f,0.f,0.f},{0.f,0.f,0.f,0.f},
                      {0.f,0.f,0.f,0.f},{0.f,0.f,0.f,0.f}};
    const int arow  = wave * 16 + m;
    const int abase = arow * KK;
    const int a7    = (arow & 7) << 3;
#pragma unroll
    for (int kt = 0; kt < 4; ++kt) {
        short8 a = *(const short8*)&Alds[abase + ((kt * 32 + kg * 8) ^ a7)];
#pragma unroll
        for (int nt = 0; nt < 4; ++nt)
            acc[nt] = __builtin_amdgcn_mfma_f32_16x16x32_bf16(a, bfrag[nt][kt], acc[nt], 0, 0, 0);
    }

    // ---- epilogue: gelu + dot(W2) + 16-lane butterfly + store ----
#pragma unroll
    for (int r = 0; r < 4; ++r) {
        const int j = j0 + wave * 16 + kg * 4 + r;   // C row = kg*4 + reg
        float s = 0.f;
#pragma unroll
        for (int nt = 0; nt < 4; ++nt) {
            float tv = acc[nt][r] + qv[nt] + kv[r][nt];
            float g = 0.5f * tv * (1.f + erff(tv * 0.70710678118654752f));
            s = fmaf(g, w2v[nt], s);
        }
#pragma unroll
        for (int off = 1; off < 16; off <<= 1) s += __shfl_xor(s, off);
        if (m == r && j <= i)
            wei[((size_t)b * TT + i) * TT + j] = (s + b2v) * 0.125f;
    }
}

// ---------------------------------------------------------------------------
// out_kernel: causal softmax over j in [0,i], then out[b,i,:] = p @ v
// PV pass vectorized: lane = (row-subgroup jr, col-quad c4) -> float4 loads.
// ---------------------------------------------------------------------------
__device__ inline float wave_reduce_max(float m) {
#pragma unroll
    for (int off = 32; off > 0; off >>= 1) m = fmaxf(m, __shfl_down(m, off));
    return m;
}
__device__ inline float wave_reduce_sum(float s) {
#pragma unroll
    for (int off = 32; off > 0; off >>= 1) s += __shfl_down(s, off);
    return s;
}

__global__ __launch_bounds__(256) void out_kernel(
    const float* __restrict__ wei, const float* __restrict__ v,
    float* __restrict__ out)
{
    const int i = blockIdx.x;
    const int b = blockIdx.y;
    const int tid = threadIdx.x;
    const int wv = tid >> 6;
    const int lane = tid & 63;
    const int n = i + 1;

    __shared__ float p[TT];
    __shared__ float red[4];
    __shared__ float4v part[4][16];

    const float* wrow = wei + ((size_t)b * TT + i) * TT;

    float mx = -1e30f;
    for (int jj = tid; jj < n; jj += 256) {
        float w = wrow[jj];
        p[jj] = w;
        mx = fmaxf(mx, w);
    }
    mx = wave_reduce_max(mx);
    if (lane == 0) red[wv] = mx;
    __syncthreads();
    const float M = fmaxf(fmaxf(red[0], red[1]), fmaxf(red[2], red[3]));
    __syncthreads();

    float s = 0.f;
    for (int jj = tid; jj < n; jj += 256) {
        float e = __expf(p[jj] - M);
        p[jj] = e;
        s += e;
    }
    s = wave_reduce_sum(s);
    if (lane == 0) red[wv] = s;
    __syncthreads();
    const float S = red[0] + red[1] + red[2] + red[3];
    const float inv = 1.f / S;

    // ---- PV: float4 per lane; wave covers 4 rows x 64 cols per iter ----
    const int c4 = lane & 15;
    const int jr = lane >> 4;
    const float4v* v4 = (const float4v*)(v + (size_t)b * TT * HH);
    float4v acc = {0.f, 0.f, 0.f, 0.f};
    for (int base = wv * 4; base < n; base += 16) {
        int j = base + jr;
        float pj = (j < n) ? p[j] : 0.f;
        int jc = (j < n) ? j : 0;            // clamp: avoid poisoned reads
        float4v vv = v4[jc * 16 + c4];
        acc += vv * pj;
    }
#pragma unroll
    for (int off = 16; off <= 32; off <<= 1) {
        float4v t;
        t[0] = __shfl_xor(acc[0], off);
        t[1] = __shfl_xor(acc[1], off);
        t[2] = __shfl_xor(acc[2], off);
        t[3] = __shfl_xor(acc[3], off);
        acc += t;
    }
    if (jr == 0) part[wv][c4] = acc;
    __syncthreads();
    if (tid < 16) {
        float4v r = (part[0][tid] + part[1][tid] + part[2][tid] + part[3][tid]) * inv;
        *((float4v*)(out + ((size_t)b * TT + i) * HH) + tid) = r;
    }
}

// ---------------------------------------------------------------------------
extern "C" void kernel_launch(void* const* d_in, const int* in_sizes, int n_in,
                              void* d_out, int out_size, void* d_ws, size_t ws_size,
                              hipStream_t stream)
{
    const float* x       = (const float*)d_in[0];
    const float* pos_emb = (const float*)d_in[1];
    const float* pd      = (const float*)d_in[2];
    const float* W1      = (const float*)d_in[3];
    const float* b1      = (const float*)d_in[4];
    const float* W2      = (const float*)d_in[5];
    const float* b2      = (const float*)d_in[6];
    const float* Wv      = (const float*)d_in[7];
    const float* bv      = (const float*)d_in[8];
    float* out = (float*)d_out;

    float* ws = (float*)d_ws;
    // layout (floats): Wpt [4096] | kp [65536] | qpb [65536] | v [65536] | wei [524288]
    unsigned short* Wpt = (unsigned short*)ws;          // 8192 ushorts
    float* kp  = ws + 4096;
    float* qpb = ws + 4096 + 65536;
    float* v   = ws + 4096 + 131072;
    float* wei = ws + 4096 + 196608;

    prep_kernel<<<dim3(BB * TT + 32), dim3(64), 0, stream>>>(x, pos_emb, W1, b1, Wv, bv, kp, qpb, v, Wpt);
    wei_kernel<<<dim3(TT / JT, TT, BB), dim3(256), 0, stream>>>(pd, Wpt, W2, b2, kp, qpb, wei);
    out_kernel<<<dim3(TT, BB), dim3(256), 0, stream>>>(wei, v, out);
}

// Round 2
// 386.745 us; speedup vs baseline: 1.2667x; 1.2667x over previous
//
#include <hip/hip_runtime.h>
#include <math.h>

#define BB 2
#define TT 512
#define CC 64
#define HH 64
#define KK 128            // 2C
#define JT 64             // j-tile per block

typedef __attribute__((ext_vector_type(8))) short short8;
typedef __attribute__((ext_vector_type(4))) float float4v;

__device__ inline unsigned short f2bf(float f) {
    unsigned int u = __float_as_uint(f);
    u = (u + 0x7FFFu + ((u >> 16) & 1u)) >> 16;   // RNE
    return (unsigned short)u;
}

// ---------------------------------------------------------------------------
// prep (+fused pack): blocks [0, BB*TT) : kp/qpb/v rows.
//                     blocks [BB*TT, BB*TT+32): pack W1p into MFMA-fragment
//                     order Wpt[((nt*4+kt)*64 + kg*16 + m)*8 + e]
//                         = bf16(W1[(2C + kt*32+kg*8+e)*C + nt*16+m])
// so wei_kernel's B loads are straight coalesced 16B/lane register loads.
// ---------------------------------------------------------------------------
__global__ __launch_bounds__(64) void prep_kernel(
    const float* __restrict__ x, const float* __restrict__ pos_emb,
    const float* __restrict__ W1, const float* __restrict__ b1,
    const float* __restrict__ Wv, const float* __restrict__ bv,
    float* __restrict__ kp, float* __restrict__ qpb, float* __restrict__ v,
    unsigned short* __restrict__ Wpt)
{
    if (blockIdx.x >= BB * TT) {
        int base = (blockIdx.x - BB * TT) * 256 + threadIdx.x;
#pragma unroll
        for (int q = 0; q < 4; ++q) {
            int o  = base + q * 64;          // 0..8191
            int e  = o & 7;
            int mm = (o >> 3) & 15;
            int kg = (o >> 7) & 3;
            int kt = (o >> 9) & 3;
            int nt = (o >> 11) & 3;
            int k = kt * 32 + kg * 8 + e;
            int c = nt * 16 + mm;
            Wpt[o] = f2bf(W1[(2 * CC + k) * CC + c]);
        }
        return;
    }

    const int row = blockIdx.x;          // b*T + t
    const int t = row & (TT - 1);
    const int c = threadIdx.x;           // 0..63
    __shared__ float xs[CC], x1s[CC];
    float xv = x[row * CC + c];
    xs[c] = xv;
    x1s[c] = xv + pos_emb[t * CC + c];
    __syncthreads();
    float ak = 0.f, aq = 0.f, av = 0.f;
#pragma unroll 8
    for (int k = 0; k < CC; ++k) {
        ak = fmaf(x1s[k], W1[k * CC + c], ak);
        aq = fmaf(x1s[k], W1[(CC + k) * CC + c], aq);
        av = fmaf(xs[k], Wv[k * HH + c], av);
    }
    kp[row * CC + c] = ak;
    qpb[row * CC + c] = aq + b1[c];
    v[row * HH + c] = av + bv[c];
}

// ---------------------------------------------------------------------------
// wei_kernel v4: B operand loaded inline (fragment-packed Wpt, L2-hot, each
// fragment used exactly once -> no register array), A tile in 16 KB
// XOR-swizzled LDS. launch_bounds(256,4): 128-VGPR budget, NO spill
// (round-1's (256,8) forced 32 VGPRs -> 220 MB scratch traffic).
// ---------------------------------------------------------------------------
__global__ __launch_bounds__(256, 4) void wei_kernel(
    const float* __restrict__ pd, const unsigned short* __restrict__ Wpt,
    const float* __restrict__ W2, const float* __restrict__ b2,
    const float* __restrict__ kp, const float* __restrict__ qpb,
    float* __restrict__ wei)
{
    const int i = blockIdx.y;
    const int b = blockIdx.z;
    const int j0 = blockIdx.x * JT;
    if (j0 > i) return;                  // uniform early exit (before barrier)

    __shared__ unsigned short Alds[JT * KK];     // 16384 B, XOR-swizzled rows

    const int tid  = threadIdx.x;
    const int wave = tid >> 6;
    const int lane = tid & 63;
    const int m    = lane & 15;
    const int kg   = lane >> 4;

    // ---- cheap epilogue prefetch (9 regs; L2-hot) ----
    float w2v[4], qv[4];
#pragma unroll
    for (int nt = 0; nt < 4; ++nt) {
        int c = nt * 16 + m;
        w2v[nt] = W2[c];
        qv[nt]  = qpb[((size_t)b * TT + i) * CC + c];
    }
    const float b2v = b2[0];

    // ---- stage A: pd fp32 -> bf16, coalesced float4 reads, swizzled LDS ----
    {
        const float4* __restrict__ p4 =
            (const float4*)(pd + (((size_t)b * TT + i) * TT + j0) * KK);
#pragma unroll
        for (int it = 0; it < 8; ++it) {
            int f = it * 256 + tid;          // 0..2047 float4
            float4 val = p4[f];
            int j  = f >> 5;                 // 32 float4 per row
            int kq = f & 31;
            uint2 u;
            u.x = (unsigned)f2bf(val.x) | ((unsigned)f2bf(val.y) << 16);
            u.y = (unsigned)f2bf(val.z) | ((unsigned)f2bf(val.w) << 16);
            *(uint2*)&Alds[j * KK + ((kq * 4) ^ ((j & 7) << 3))] = u;
        }
    }
    __syncthreads();

    // ---- MFMA: 4 ds_read_b128 + 16 inline B loads + 16 MFMA per lane ----
    float4v acc[4] = {{0.f,0.f,0.f,0.f},{0.f,0.f,0.f,0.f},
                      {0.f,0.f,0.f,0.f},{0.f,0.f,0.f,0.f}};
    const int arow  = wave * 16 + m;
    const int abase = arow * KK;
    const int a7    = (arow & 7) << 3;
#pragma unroll
    for (int kt = 0; kt < 4; ++kt) {
        short8 a = *(const short8*)&Alds[abase + ((kt * 32 + kg * 8) ^ a7)];
#pragma unroll
        for (int nt = 0; nt < 4; ++nt) {
            short8 bf = *(const short8*)&Wpt[((nt * 4 + kt) * 64 + lane) * 8];
            acc[nt] = __builtin_amdgcn_mfma_f32_16x16x32_bf16(a, bf, acc[nt], 0, 0, 0);
        }
    }

    // ---- epilogue: gelu + dot(W2) + 16-lane butterfly + store ----
#pragma unroll
    for (int r = 0; r < 4; ++r) {
        const int j = j0 + wave * 16 + kg * 4 + r;   // C row = kg*4 + reg
        float s = 0.f;
#pragma unroll
        for (int nt = 0; nt < 4; ++nt) {
            float tv = acc[nt][r] + qv[nt]
                     + kp[((size_t)b * TT + j) * CC + nt * 16 + m];
            float g = 0.5f * tv * (1.f + erff(tv * 0.70710678118654752f));
            s = fmaf(g, w2v[nt], s);
        }
#pragma unroll
        for (int off = 1; off < 16; off <<= 1) s += __shfl_xor(s, off);
        if (m == r && j <= i)
            wei[((size_t)b * TT + i) * TT + j] = (s + b2v) * 0.125f;
    }
}

// ---------------------------------------------------------------------------
// out_kernel: causal softmax over j in [0,i], then out[b,i,:] = p @ v
// PV pass vectorized: lane = (row-subgroup jr, col-quad c4) -> float4 loads.
// ---------------------------------------------------------------------------
__device__ inline float wave_reduce_max(float m) {
#pragma unroll
    for (int off = 32; off > 0; off >>= 1) m = fmaxf(m, __shfl_down(m, off));
    return m;
}
__device__ inline float wave_reduce_sum(float s) {
#pragma unroll
    for (int off = 32; off > 0; off >>= 1) s += __shfl_down(s, off);
    return s;
}

__global__ __launch_bounds__(256) void out_kernel(
    const float* __restrict__ wei, const float* __restrict__ v,
    float* __restrict__ out)
{
    const int i = blockIdx.x;
    const int b = blockIdx.y;
    const int tid = threadIdx.x;
    const int wv = tid >> 6;
    const int lane = tid & 63;
    const int n = i + 1;

    __shared__ float p[TT];
    __shared__ float red[4];
    __shared__ float4v part[4][16];

    const float* wrow = wei + ((size_t)b * TT + i) * TT;

    float mx = -1e30f;
    for (int jj = tid; jj < n; jj += 256) {
        float w = wrow[jj];
        p[jj] = w;
        mx = fmaxf(mx, w);
    }
    mx = wave_reduce_max(mx);
    if (lane == 0) red[wv] = mx;
    __syncthreads();
    const float M = fmaxf(fmaxf(red[0], red[1]), fmaxf(red[2], red[3]));
    __syncthreads();

    float s = 0.f;
    for (int jj = tid; jj < n; jj += 256) {
        float e = __expf(p[jj] - M);
        p[jj] = e;
        s += e;
    }
    s = wave_reduce_sum(s);
    if (lane == 0) red[wv] = s;
    __syncthreads();
    const float S = red[0] + red[1] + red[2] + red[3];
    const float inv = 1.f / S;

    // ---- PV: float4 per lane; wave covers 4 rows x 64 cols per iter ----
    const int c4 = lane & 15;
    const int jr = lane >> 4;
    const float4v* v4 = (const float4v*)(v + (size_t)b * TT * HH);
    float4v acc = {0.f, 0.f, 0.f, 0.f};
    for (int base = wv * 4; base < n; base += 16) {
        int j = base + jr;
        float pj = (j < n) ? p[j] : 0.f;
        int jc = (j < n) ? j : 0;            // clamp: avoid poisoned reads
        float4v vv = v4[jc * 16 + c4];
        acc += vv * pj;
    }
#pragma unroll
    for (int off = 16; off <= 32; off <<= 1) {
        float4v t;
        t[0] = __shfl_xor(acc[0], off);
        t[1] = __shfl_xor(acc[1], off);
        t[2] = __shfl_xor(acc[2], off);
        t[3] = __shfl_xor(acc[3], off);
        acc += t;
    }
    if (jr == 0) part[wv][c4] = acc;
    __syncthreads();
    if (tid < 16) {
        float4v r = (part[0][tid] + part[1][tid] + part[2][tid] + part[3][tid]) * inv;
        *((float4v*)(out + ((size_t)b * TT + i) * HH) + tid) = r;
    }
}

// ---------------------------------------------------------------------------
extern "C" void kernel_launch(void* const* d_in, const int* in_sizes, int n_in,
                              void* d_out, int out_size, void* d_ws, size_t ws_size,
                              hipStream_t stream)
{
    const float* x       = (const float*)d_in[0];
    const float* pos_emb = (const float*)d_in[1];
    const float* pd      = (const float*)d_in[2];
    const float* W1      = (const float*)d_in[3];
    const float* b1      = (const float*)d_in[4];
    const float* W2      = (const float*)d_in[5];
    const float* b2      = (const float*)d_in[6];
    const float* Wv      = (const float*)d_in[7];
    const float* bv      = (const float*)d_in[8];
    float* out = (float*)d_out;

    float* ws = (float*)d_ws;
    // layout (floats): Wpt [4096] | kp [65536] | qpb [65536] | v [65536] | wei [524288]
    unsigned short* Wpt = (unsigned short*)ws;          // 8192 ushorts
    float* kp  = ws + 4096;
    float* qpb = ws + 4096 + 65536;
    float* v   = ws + 4096 + 131072;
    float* wei = ws + 4096 + 196608;

    prep_kernel<<<dim3(BB * TT + 32), dim3(64), 0, stream>>>(x, pos_emb, W1, b1, Wv, bv, kp, qpb, v, Wpt);
    wei_kernel<<<dim3(TT / JT, TT, BB), dim3(256), 0, stream>>>(pd, Wpt, W2, b2, kp, qpb, wei);
    out_kernel<<<dim3(TT, BB), dim3(256), 0, stream>>>(wei, v, out);
}

// Round 3
// 376.585 us; speedup vs baseline: 1.3008x; 1.0270x over previous
//
#include <hip/hip_runtime.h>
#include <math.h>

#define BB 2
#define TT 512
#define CC 64
#define HH 64
#define KK 128            // 2C
#define JT 64             // j-tile

typedef __attribute__((ext_vector_type(8))) short short8;
typedef __attribute__((ext_vector_type(4))) float float4v;

__device__ inline unsigned short f2bf(float f) {
    unsigned int u = __float_as_uint(f);
    u = (u + 0x7FFFu + ((u >> 16) & 1u)) >> 16;   // RNE
    return (unsigned short)u;
}

// ---------------------------------------------------------------------------
// prep (+fused pack): blocks [0, BB*TT) : kp/qpb/v rows.
//                     blocks [BB*TT, BB*TT+32): pack W1p into MFMA-fragment
//                     order Wpt[((nt*4+kt)*64 + lane)*8 + e]
//                         = bf16(W1[(2C + kt*32+(lane>>4)*8+e)*C + nt*16+(lane&15)])
// ---------------------------------------------------------------------------
__global__ __launch_bounds__(64) void prep_kernel(
    const float* __restrict__ x, const float* __restrict__ pos_emb,
    const float* __restrict__ W1, const float* __restrict__ b1,
    const float* __restrict__ Wv, const float* __restrict__ bv,
    float* __restrict__ kp, float* __restrict__ qpb, float* __restrict__ v,
    unsigned short* __restrict__ Wpt)
{
    if (blockIdx.x >= BB * TT) {
        int base = (blockIdx.x - BB * TT) * 256 + threadIdx.x;
#pragma unroll
        for (int q = 0; q < 4; ++q) {
            int o  = base + q * 64;          // 0..8191
            int e  = o & 7;
            int mm = (o >> 3) & 15;
            int kg = (o >> 7) & 3;
            int kt = (o >> 9) & 3;
            int nt = (o >> 11) & 3;
            int k = kt * 32 + kg * 8 + e;
            int c = nt * 16 + mm;
            Wpt[o] = f2bf(W1[(2 * CC + k) * CC + c]);
        }
        return;
    }

    const int row = blockIdx.x;          // b*T + t
    const int t = row & (TT - 1);
    const int c = threadIdx.x;           // 0..63
    __shared__ float xs[CC], x1s[CC];
    float xv = x[row * CC + c];
    xs[c] = xv;
    x1s[c] = xv + pos_emb[t * CC + c];
    __syncthreads();
    float ak = 0.f, aq = 0.f, av = 0.f;
#pragma unroll 8
    for (int k = 0; k < CC; ++k) {
        ak = fmaf(x1s[k], W1[k * CC + c], ak);
        aq = fmaf(x1s[k], W1[(CC + k) * CC + c], aq);
        av = fmaf(xs[k], Wv[k * HH + c], av);
    }
    kp[row * CC + c] = ak;
    qpb[row * CC + c] = aq + b1[c];
    v[row * HH + c] = av + bv[c];
}

// ---------------------------------------------------------------------------
// fused_kernel: one block per (b, i). Loops causal j-tiles:
//   acc init = kp[j,c] + qpb[i,c]  (pre-barrier global loads -> acc regs)
//   stage pd tile fp32->bf16 into XOR-swizzled Alds (rows j>i skipped)
//   MFMA 4x4 (A from Alds, B from per-block Blds copy of Wpt)
//   epilogue: gelu + dot(W2) + butterfly -> p[j] in LDS
// then block-local softmax over p[0..i] and PV: out[b,i,:] = p @ v.
// wei never touches global memory; no separate out_kernel launch.
// ---------------------------------------------------------------------------
__global__ __launch_bounds__(256, 4) void fused_kernel(
    const float* __restrict__ pd, const unsigned short* __restrict__ Wpt,
    const float* __restrict__ W2, const float* __restrict__ b2,
    const float* __restrict__ kp, const float* __restrict__ qpb,
    const float* __restrict__ v, float* __restrict__ out)
{
    const int i = blockIdx.x;
    const int b = blockIdx.y;
    const int tid  = threadIdx.x;
    const int wave = tid >> 6;
    const int lane = tid & 63;
    const int m    = lane & 15;
    const int kg   = lane >> 4;

    __shared__ unsigned short Alds[JT * KK];     // 16 KB, XOR-swizzled rows
    __shared__ unsigned short Blds[16 * 64 * 8]; // 16 KB, fragment-ordered
    __shared__ float p[TT];                      // 2 KB wei row
    __shared__ float red[4];
    __shared__ float4v part[4][16];

    // ---- Blds: one-time copy of fragment-packed Wpt (L2-hot) ----
    {
        const uint4* __restrict__ src = (const uint4*)Wpt;
        uint4* dst = (uint4*)Blds;
#pragma unroll
        for (int f = 0; f < 4; ++f) dst[f * 256 + tid] = src[f * 256 + tid];
    }

    // ---- per-row constants ----
    float w2v[4], qv[4];
#pragma unroll
    for (int nt = 0; nt < 4; ++nt) {
        int c = nt * 16 + m;
        w2v[nt] = W2[c];
        qv[nt]  = qpb[((size_t)b * TT + i) * CC + c];
    }
    const float b2v = b2[0];

    const float* __restrict__ kprow = kp + (size_t)b * TT * CC;
    const int ntiles = (i >> 6) + 1;

    for (int jt = 0; jt < ntiles; ++jt) {
        const int j0 = jt * JT;

        // ---- acc init = kp + qp (+b1): folds epilogue adds into C-operand;
        //      global loads issued pre-barrier, latency hides under staging ----
        float4v acc[4];
#pragma unroll
        for (int r = 0; r < 4; ++r) {
            int j = j0 + wave * 16 + kg * 4 + r;
#pragma unroll
            for (int nt = 0; nt < 4; ++nt)
                acc[nt][r] = kprow[j * CC + nt * 16 + m] + qv[nt];
        }

        __syncthreads();   // prev-iter MFMA readers done; Blds copy visible (iter 0)

        // ---- stage A: pd fp32 -> bf16, swizzled; skip rows j > i ----
        {
            const float4* __restrict__ p4 =
                (const float4*)(pd + (((size_t)b * TT + i) * TT + j0) * KK);
#pragma unroll
            for (int it = 0; it < 8; ++it) {
                int f = it * 256 + tid;          // 0..2047 float4
                int j  = f >> 5;                 // 32 float4 per row
                int kq = f & 31;
                if (j0 + j <= i) {
                    float4 val = p4[f];
                    uint2 u;
                    u.x = (unsigned)f2bf(val.x) | ((unsigned)f2bf(val.y) << 16);
                    u.y = (unsigned)f2bf(val.z) | ((unsigned)f2bf(val.w) << 16);
                    *(uint2*)&Alds[j * KK + ((kq * 4) ^ ((j & 7) << 3))] = u;
                }
            }
        }
        __syncthreads();

        // ---- MFMA: 4 A-ds_reads + 16 B-ds_reads + 16 MFMA ----
        const int arow  = wave * 16 + m;
        const int abase = arow * KK;
        const int a7    = (arow & 7) << 3;
#pragma unroll
        for (int kt = 0; kt < 4; ++kt) {
            short8 a = *(const short8*)&Alds[abase + ((kt * 32 + kg * 8) ^ a7)];
#pragma unroll
            for (int nt = 0; nt < 4; ++nt) {
                short8 bf = *(const short8*)&Blds[((nt * 4 + kt) * 64 + lane) * 8];
                acc[nt] = __builtin_amdgcn_mfma_f32_16x16x32_bf16(a, bf, acc[nt], 0, 0, 0);
            }
        }

        // ---- epilogue: pure VALU (kp/qp already in acc) ----
#pragma unroll
        for (int r = 0; r < 4; ++r) {
            float s = 0.f;
#pragma unroll
            for (int nt = 0; nt < 4; ++nt) {
                float tv = acc[nt][r];
                float g = 0.5f * tv * (1.f + erff(tv * 0.70710678118654752f));
                s = fmaf(g, w2v[nt], s);
            }
#pragma unroll
            for (int off = 1; off < 16; off <<= 1) s += __shfl_xor(s, off);
            const int j = j0 + wave * 16 + kg * 4 + r;
            if (m == r && j <= i) p[j] = (s + b2v) * 0.125f;
        }
    }
    __syncthreads();   // p[0..i] complete

    // ---- softmax over p[0..i] ----
    const int n = i + 1;
    float mx = -1e30f;
    for (int jj = tid; jj < n; jj += 256) mx = fmaxf(mx, p[jj]);
#pragma unroll
    for (int off = 32; off > 0; off >>= 1) mx = fmaxf(mx, __shfl_down(mx, off));
    if (lane == 0) red[wave] = mx;
    __syncthreads();
    const float M = fmaxf(fmaxf(red[0], red[1]), fmaxf(red[2], red[3]));
    __syncthreads();

    float s = 0.f;
    for (int jj = tid; jj < n; jj += 256) {
        float e = __expf(p[jj] - M);
        p[jj] = e;
        s += e;
    }
#pragma unroll
    for (int off = 32; off > 0; off >>= 1) s += __shfl_down(s, off);
    if (lane == 0) red[wave] = s;
    __syncthreads();
    const float S = red[0] + red[1] + red[2] + red[3];
    const float inv = 1.f / S;

    // ---- PV: float4 per lane; wave covers 4 rows x 64 cols per iter ----
    const int c4 = lane & 15;
    const int jr = lane >> 4;
    const float4v* v4 = (const float4v*)(v + (size_t)b * TT * HH);
    float4v acc = {0.f, 0.f, 0.f, 0.f};
    for (int base = wave * 4; base < n; base += 16) {
        int j = base + jr;
        float pj = (j < n) ? p[j] : 0.f;
        int jc = (j < n) ? j : 0;            // clamp: avoid stray reads
        float4v vv = v4[jc * 16 + c4];
        acc += vv * pj;
    }
#pragma unroll
    for (int off = 16; off <= 32; off <<= 1) {
        float4v t;
        t[0] = __shfl_xor(acc[0], off);
        t[1] = __shfl_xor(acc[1], off);
        t[2] = __shfl_xor(acc[2], off);
        t[3] = __shfl_xor(acc[3], off);
        acc += t;
    }
    if (jr == 0) part[wave][c4] = acc;
    __syncthreads();
    if (tid < 16) {
        float4v r = (part[0][tid] + part[1][tid] + part[2][tid] + part[3][tid]) * inv;
        *((float4v*)(out + ((size_t)b * TT + i) * HH) + tid) = r;
    }
}

// ---------------------------------------------------------------------------
extern "C" void kernel_launch(void* const* d_in, const int* in_sizes, int n_in,
                              void* d_out, int out_size, void* d_ws, size_t ws_size,
                              hipStream_t stream)
{
    const float* x       = (const float*)d_in[0];
    const float* pos_emb = (const float*)d_in[1];
    const float* pd      = (const float*)d_in[2];
    const float* W1      = (const float*)d_in[3];
    const float* b1      = (const float*)d_in[4];
    const float* W2      = (const float*)d_in[5];
    const float* b2      = (const float*)d_in[6];
    const float* Wv      = (const float*)d_in[7];
    const float* bv      = (const float*)d_in[8];
    float* out = (float*)d_out;

    float* ws = (float*)d_ws;
    // layout (floats): Wpt [4096] | kp [65536] | qpb [65536] | v [65536]
    unsigned short* Wpt = (unsigned short*)ws;          // 8192 ushorts
    float* kp  = ws + 4096;
    float* qpb = ws + 4096 + 65536;
    float* v   = ws + 4096 + 131072;

    prep_kernel<<<dim3(BB * TT + 32), dim3(64), 0, stream>>>(x, pos_emb, W1, b1, Wv, bv, kp, qpb, v, Wpt);
    fused_kernel<<<dim3(TT, BB), dim3(256), 0, stream>>>(pd, Wpt, W2, b2, kp, qpb, v, out);
}

// Round 4
// 375.209 us; speedup vs baseline: 1.3056x; 1.0037x over previous
//
#include <hip/hip_runtime.h>
#include <math.h>

#define BB 2
#define TT 512
#define CC 64
#define HH 64
#define KK 128            // 2C
#define JT 64             // j-tile

typedef __attribute__((ext_vector_type(8))) short short8;
typedef __attribute__((ext_vector_type(4))) float float4v;

__device__ inline unsigned short f2bf(float f) {
    unsigned int u = __float_as_uint(f);
    u = (u + 0x7FFFu + ((u >> 16) & 1u)) >> 16;   // RNE
    return (unsigned short)u;
}

// ---------------------------------------------------------------------------
// prep (+fused pack): blocks [0, BB*TT) : kp/qpb/v rows.
//                     blocks [BB*TT, BB*TT+32): pack W1p into MFMA-fragment
//                     order Wpt[((nt*4+kt)*64 + lane)*8 + e]
// ---------------------------------------------------------------------------
__global__ __launch_bounds__(64) void prep_kernel(
    const float* __restrict__ x, const float* __restrict__ pos_emb,
    const float* __restrict__ W1, const float* __restrict__ b1,
    const float* __restrict__ Wv, const float* __restrict__ bv,
    float* __restrict__ kp, float* __restrict__ qpb, float* __restrict__ v,
    unsigned short* __restrict__ Wpt)
{
    if (blockIdx.x >= BB * TT) {
        int base = (blockIdx.x - BB * TT) * 256 + threadIdx.x;
#pragma unroll
        for (int q = 0; q < 4; ++q) {
            int o  = base + q * 64;          // 0..8191
            int e  = o & 7;
            int mm = (o >> 3) & 15;
            int kg = (o >> 7) & 3;
            int kt = (o >> 9) & 3;
            int nt = (o >> 11) & 3;
            int k = kt * 32 + kg * 8 + e;
            int c = nt * 16 + mm;
            Wpt[o] = f2bf(W1[(2 * CC + k) * CC + c]);
        }
        return;
    }

    const int row = blockIdx.x;          // b*T + t
    const int t = row & (TT - 1);
    const int c = threadIdx.x;           // 0..63
    __shared__ float xs[CC], x1s[CC];
    float xv = x[row * CC + c];
    xs[c] = xv;
    x1s[c] = xv + pos_emb[t * CC + c];
    __syncthreads();
    float ak = 0.f, aq = 0.f, av = 0.f;
#pragma unroll 8
    for (int k = 0; k < CC; ++k) {
        ak = fmaf(x1s[k], W1[k * CC + c], ak);
        aq = fmaf(x1s[k], W1[(CC + k) * CC + c], aq);
        av = fmaf(xs[k], Wv[k * HH + c], av);
    }
    kp[row * CC + c] = ak;
    qpb[row * CC + c] = aq + b1[c];
    v[row * HH + c] = av + bv[c];
}

// ---------------------------------------------------------------------------
// fused_kernel: one block per (b, i). Causal-balanced i remap:
//   gx -> i = (gx<256) ? 2*gx : 1023-2*gx
// pairs heavy rows with light rows on the same CU under round-robin dispatch
// (per-CU tile totals flatten 12..24 -> 18..20). Correctness is mapping-
// independent (bijection on [0,512)).
// Per j-tile: acc init = kp[j,c]+qpb[i,c] (pre-barrier); stage pd fp32->bf16
// into XOR-swizzled Alds (rows j>i skipped); MFMA 4x4; gelu+dot(W2) -> p[j].
// Then block-local softmax + PV. wei never touches global.
// ---------------------------------------------------------------------------
__global__ __launch_bounds__(256, 4) void fused_kernel(
    const float* __restrict__ pd, const unsigned short* __restrict__ Wpt,
    const float* __restrict__ W2, const float* __restrict__ b2,
    const float* __restrict__ kp, const float* __restrict__ qpb,
    const float* __restrict__ v, float* __restrict__ out)
{
    const int gx = blockIdx.x;
    const int i = (gx < 256) ? (gx << 1) : (1023 - (gx << 1));
    const int b = blockIdx.y;
    const int tid  = threadIdx.x;
    const int wave = tid >> 6;
    const int lane = tid & 63;
    const int m    = lane & 15;
    const int kg   = lane >> 4;

    __shared__ unsigned short Alds[JT * KK];     // 16 KB, XOR-swizzled rows
    __shared__ unsigned short Blds[16 * 64 * 8]; // 16 KB, fragment-ordered
    __shared__ float p[TT];                      // 2 KB wei row
    __shared__ float red[4];
    __shared__ float4v part[4][16];

    // ---- Blds: one-time copy of fragment-packed Wpt (L2-hot) ----
    {
        const uint4* __restrict__ src = (const uint4*)Wpt;
        uint4* dst = (uint4*)Blds;
#pragma unroll
        for (int f = 0; f < 4; ++f) dst[f * 256 + tid] = src[f * 256 + tid];
    }

    // ---- per-row constants ----
    float w2v[4], qv[4];
#pragma unroll
    for (int nt = 0; nt < 4; ++nt) {
        int c = nt * 16 + m;
        w2v[nt] = W2[c];
        qv[nt]  = qpb[((size_t)b * TT + i) * CC + c];
    }
    const float b2v = b2[0];

    const float* __restrict__ kprow = kp + (size_t)b * TT * CC;
    const int ntiles = (i >> 6) + 1;

    for (int jt = 0; jt < ntiles; ++jt) {
        const int j0 = jt * JT;

        // ---- acc init = kp + qp (+b1): folds epilogue adds into C-operand ----
        float4v acc[4];
#pragma unroll
        for (int r = 0; r < 4; ++r) {
            int j = j0 + wave * 16 + kg * 4 + r;
#pragma unroll
            for (int nt = 0; nt < 4; ++nt)
                acc[nt][r] = kprow[j * CC + nt * 16 + m] + qv[nt];
        }

        __syncthreads();   // prev-iter MFMA readers done; Blds visible (iter 0)

        // ---- stage A: pd fp32 -> bf16, swizzled; skip rows j > i ----
        {
            const float4* __restrict__ p4 =
                (const float4*)(pd + (((size_t)b * TT + i) * TT + j0) * KK);
#pragma unroll
            for (int it = 0; it < 8; ++it) {
                int f = it * 256 + tid;          // 0..2047 float4
                int j  = f >> 5;                 // 32 float4 per row
                int kq = f & 31;
                if (j0 + j <= i) {
                    float4 val = p4[f];
                    uint2 u;
                    u.x = (unsigned)f2bf(val.x) | ((unsigned)f2bf(val.y) << 16);
                    u.y = (unsigned)f2bf(val.z) | ((unsigned)f2bf(val.w) << 16);
                    *(uint2*)&Alds[j * KK + ((kq * 4) ^ ((j & 7) << 3))] = u;
                }
            }
        }
        __syncthreads();

        // ---- MFMA: 4 A-ds_reads + 16 B-ds_reads + 16 MFMA ----
        const int arow  = wave * 16 + m;
        const int abase = arow * KK;
        const int a7    = (arow & 7) << 3;
#pragma unroll
        for (int kt = 0; kt < 4; ++kt) {
            short8 a = *(const short8*)&Alds[abase + ((kt * 32 + kg * 8) ^ a7)];
#pragma unroll
            for (int nt = 0; nt < 4; ++nt) {
                short8 bf = *(const short8*)&Blds[((nt * 4 + kt) * 64 + lane) * 8];
                acc[nt] = __builtin_amdgcn_mfma_f32_16x16x32_bf16(a, bf, acc[nt], 0, 0, 0);
            }
        }

        // ---- epilogue: pure VALU (kp/qp already in acc) ----
#pragma unroll
        for (int r = 0; r < 4; ++r) {
            float s = 0.f;
#pragma unroll
            for (int nt = 0; nt < 4; ++nt) {
                float tv = acc[nt][r];
                float g = 0.5f * tv * (1.f + erff(tv * 0.70710678118654752f));
                s = fmaf(g, w2v[nt], s);
            }
#pragma unroll
            for (int off = 1; off < 16; off <<= 1) s += __shfl_xor(s, off);
            const int j = j0 + wave * 16 + kg * 4 + r;
            if (m == r && j <= i) p[j] = (s + b2v) * 0.125f;
        }
    }
    __syncthreads();   // p[0..i] complete

    // ---- softmax over p[0..i] ----
    const int n = i + 1;
    float mx = -1e30f;
    for (int jj = tid; jj < n; jj += 256) mx = fmaxf(mx, p[jj]);
#pragma unroll
    for (int off = 32; off > 0; off >>= 1) mx = fmaxf(mx, __shfl_down(mx, off));
    if (lane == 0) red[wave] = mx;
    __syncthreads();
    const float M = fmaxf(fmaxf(red[0], red[1]), fmaxf(red[2], red[3]));
    __syncthreads();

    float s = 0.f;
    for (int jj = tid; jj < n; jj += 256) {
        float e = __expf(p[jj] - M);
        p[jj] = e;
        s += e;
    }
#pragma unroll
    for (int off = 32; off > 0; off >>= 1) s += __shfl_down(s, off);
    if (lane == 0) red[wave] = s;
    __syncthreads();
    const float S = red[0] + red[1] + red[2] + red[3];
    const float inv = 1.f / S;

    // ---- PV: float4 per lane; wave covers 4 rows x 64 cols per iter ----
    const int c4 = lane & 15;
    const int jr = lane >> 4;
    const float4v* v4 = (const float4v*)(v + (size_t)b * TT * HH);
    float4v acc = {0.f, 0.f, 0.f, 0.f};
    for (int base = wave * 4; base < n; base += 16) {
        int j = base + jr;
        float pj = (j < n) ? p[j] : 0.f;
        int jc = (j < n) ? j : 0;            // clamp: avoid stray reads
        float4v vv = v4[jc * 16 + c4];
        acc += vv * pj;
    }
#pragma unroll
    for (int off = 16; off <= 32; off <<= 1) {
        float4v t;
        t[0] = __shfl_xor(acc[0], off);
        t[1] = __shfl_xor(acc[1], off);
        t[2] = __shfl_xor(acc[2], off);
        t[3] = __shfl_xor(acc[3], off);
        acc += t;
    }
    if (jr == 0) part[wave][c4] = acc;
    __syncthreads();
    if (tid < 16) {
        float4v r = (part[0][tid] + part[1][tid] + part[2][tid] + part[3][tid]) * inv;
        *((float4v*)(out + ((size_t)b * TT + i) * HH) + tid) = r;
    }
}

// ---------------------------------------------------------------------------
extern "C" void kernel_launch(void* const* d_in, const int* in_sizes, int n_in,
                              void* d_out, int out_size, void* d_ws, size_t ws_size,
                              hipStream_t stream)
{
    const float* x       = (const float*)d_in[0];
    const float* pos_emb = (const float*)d_in[1];
    const float* pd      = (const float*)d_in[2];
    const float* W1      = (const float*)d_in[3];
    const float* b1      = (const float*)d_in[4];
    const float* W2      = (const float*)d_in[5];
    const float* b2      = (const float*)d_in[6];
    const float* Wv      = (const float*)d_in[7];
    const float* bv      = (const float*)d_in[8];
    float* out = (float*)d_out;

    float* ws = (float*)d_ws;
    // layout (floats): Wpt [4096] | kp [65536] | qpb [65536] | v [65536]
    unsigned short* Wpt = (unsigned short*)ws;          // 8192 ushorts
    float* kp  = ws + 4096;
    float* qpb = ws + 4096 + 65536;
    float* v   = ws + 4096 + 131072;

    prep_kernel<<<dim3(BB * TT + 32), dim3(64), 0, stream>>>(x, pos_emb, W1, b1, Wv, bv, kp, qpb, v, Wpt);
    fused_kernel<<<dim3(TT, BB), dim3(256), 0, stream>>>(pd, Wpt, W2, b2, kp, qpb, v, out);
}

// Round 5
// 373.057 us; speedup vs baseline: 1.3131x; 1.0058x over previous
//
#include <hip/hip_runtime.h>
#include <math.h>

#define BB 2
#define TT 512
#define CC 64
#define HH 64
#define KK 128            // 2C
#define JT 64             // j-tile

typedef __attribute__((ext_vector_type(8))) short short8;
typedef __attribute__((ext_vector_type(4))) float float4v;

__device__ inline unsigned short f2bf(float f) {
    unsigned int u = __float_as_uint(f);
    u = (u + 0x7FFFu + ((u >> 16) & 1u)) >> 16;   // RNE
    return (unsigned short)u;
}

// Branch-free gelu: erf via Abramowitz-Stegun 7.1.26 (max err 1.5e-7).
// ~16 VALU + 1 v_exp_f32; library erff is branchy (~50 effective ops
// under divergence) and was a co-bottleneck with the pd HBM stream.
__device__ inline float gelu_fast(float tv) {
    float z  = tv * 0.70710678118654752f;
    float az = fabsf(z);
    float t  = __builtin_amdgcn_rcpf(fmaf(0.3275911f, az, 1.f));
    float e  = __expf(-az * az);
    float p  = fmaf(1.061405429f, t, -1.453152027f);
    p = fmaf(p, t, 1.421413741f);
    p = fmaf(p, t, -0.284496736f);
    p = fmaf(p, t, 0.254829592f);
    p = p * t;
    float er = copysignf(fmaf(-p, e, 1.f), z);
    return 0.5f * tv * (1.f + er);
}

// ---------------------------------------------------------------------------
// prep (+fused pack): blocks [0, BB*TT) : kp/qpb/v rows.
//                     blocks [BB*TT, BB*TT+32): pack W1p into MFMA-fragment
//                     order Wpt[((nt*4+kt)*64 + lane)*8 + e]
// ---------------------------------------------------------------------------
__global__ __launch_bounds__(64) void prep_kernel(
    const float* __restrict__ x, const float* __restrict__ pos_emb,
    const float* __restrict__ W1, const float* __restrict__ b1,
    const float* __restrict__ Wv, const float* __restrict__ bv,
    float* __restrict__ kp, float* __restrict__ qpb, float* __restrict__ v,
    unsigned short* __restrict__ Wpt)
{
    if (blockIdx.x >= BB * TT) {
        int base = (blockIdx.x - BB * TT) * 256 + threadIdx.x;
#pragma unroll
        for (int q = 0; q < 4; ++q) {
            int o  = base + q * 64;          // 0..8191
            int e  = o & 7;
            int mm = (o >> 3) & 15;
            int kg = (o >> 7) & 3;
            int kt = (o >> 9) & 3;
            int nt = (o >> 11) & 3;
            int k = kt * 32 + kg * 8 + e;
            int c = nt * 16 + mm;
            Wpt[o] = f2bf(W1[(2 * CC + k) * CC + c]);
        }
        return;
    }

    const int row = blockIdx.x;          // b*T + t
    const int t = row & (TT - 1);
    const int c = threadIdx.x;           // 0..63
    __shared__ float xs[CC], x1s[CC];
    float xv = x[row * CC + c];
    xs[c] = xv;
    x1s[c] = xv + pos_emb[t * CC + c];
    __syncthreads();
    float ak = 0.f, aq = 0.f, av = 0.f;
#pragma unroll 8
    for (int k = 0; k < CC; ++k) {
        ak = fmaf(x1s[k], W1[k * CC + c], ak);
        aq = fmaf(x1s[k], W1[(CC + k) * CC + c], aq);
        av = fmaf(xs[k], Wv[k * HH + c], av);
    }
    kp[row * CC + c] = ak;
    qpb[row * CC + c] = aq + b1[c];
    v[row * HH + c] = av + bv[c];
}

// ---------------------------------------------------------------------------
// fused_kernel: one block per (b, i), causal-balanced i remap (kept from R4,
// neutral-not-harmful). Per j-tile: acc init = kp[j,c]+qpb[i,c] (pre-barrier);
// stage pd fp32->bf16 into XOR-swizzled Alds (rows j>i skipped); MFMA 4x4;
// fast-gelu + dot(W2) -> p[j] in LDS. Then block softmax + PV.
// ---------------------------------------------------------------------------
__global__ __launch_bounds__(256, 4) void fused_kernel(
    const float* __restrict__ pd, const unsigned short* __restrict__ Wpt,
    const float* __restrict__ W2, const float* __restrict__ b2,
    const float* __restrict__ kp, const float* __restrict__ qpb,
    const float* __restrict__ v, float* __restrict__ out)
{
    const int gx = blockIdx.x;
    const int i = (gx < 256) ? (gx << 1) : (1023 - (gx << 1));
    const int b = blockIdx.y;
    const int tid  = threadIdx.x;
    const int wave = tid >> 6;
    const int lane = tid & 63;
    const int m    = lane & 15;
    const int kg   = lane >> 4;

    __shared__ unsigned short Alds[JT * KK];     // 16 KB, XOR-swizzled rows
    __shared__ unsigned short Blds[16 * 64 * 8]; // 16 KB, fragment-ordered
    __shared__ float p[TT];                      // 2 KB wei row
    __shared__ float red[4];
    __shared__ float4v part[4][16];

    // ---- Blds: one-time copy of fragment-packed Wpt (L2-hot) ----
    {
        const uint4* __restrict__ src = (const uint4*)Wpt;
        uint4* dst = (uint4*)Blds;
#pragma unroll
        for (int f = 0; f < 4; ++f) dst[f * 256 + tid] = src[f * 256 + tid];
    }

    // ---- per-row constants ----
    float w2v[4], qv[4];
#pragma unroll
    for (int nt = 0; nt < 4; ++nt) {
        int c = nt * 16 + m;
        w2v[nt] = W2[c];
        qv[nt]  = qpb[((size_t)b * TT + i) * CC + c];
    }
    const float b2v = b2[0];

    const float* __restrict__ kprow = kp + (size_t)b * TT * CC;
    const int ntiles = (i >> 6) + 1;

    for (int jt = 0; jt < ntiles; ++jt) {
        const int j0 = jt * JT;

        // ---- acc init = kp + qp (+b1): folds epilogue adds into C-operand ----
        float4v acc[4];
#pragma unroll
        for (int r = 0; r < 4; ++r) {
            int j = j0 + wave * 16 + kg * 4 + r;
#pragma unroll
            for (int nt = 0; nt < 4; ++nt)
                acc[nt][r] = kprow[j * CC + nt * 16 + m] + qv[nt];
        }

        __syncthreads();   // prev-iter MFMA readers done; Blds visible (iter 0)

        // ---- stage A: pd fp32 -> bf16, swizzled; skip rows j > i ----
        {
            const float4* __restrict__ p4 =
                (const float4*)(pd + (((size_t)b * TT + i) * TT + j0) * KK);
#pragma unroll
            for (int it = 0; it < 8; ++it) {
                int f = it * 256 + tid;          // 0..2047 float4
                int j  = f >> 5;                 // 32 float4 per row
                int kq = f & 31;
                if (j0 + j <= i) {
                    float4 val = p4[f];
                    uint2 u;
                    u.x = (unsigned)f2bf(val.x) | ((unsigned)f2bf(val.y) << 16);
                    u.y = (unsigned)f2bf(val.z) | ((unsigned)f2bf(val.w) << 16);
                    *(uint2*)&Alds[j * KK + ((kq * 4) ^ ((j & 7) << 3))] = u;
                }
            }
        }
        __syncthreads();

        // ---- MFMA: 4 A-ds_reads + 16 B-ds_reads + 16 MFMA ----
        const int arow  = wave * 16 + m;
        const int abase = arow * KK;
        const int a7    = (arow & 7) << 3;
#pragma unroll
        for (int kt = 0; kt < 4; ++kt) {
            short8 a = *(const short8*)&Alds[abase + ((kt * 32 + kg * 8) ^ a7)];
#pragma unroll
            for (int nt = 0; nt < 4; ++nt) {
                short8 bf = *(const short8*)&Blds[((nt * 4 + kt) * 64 + lane) * 8];
                acc[nt] = __builtin_amdgcn_mfma_f32_16x16x32_bf16(a, bf, acc[nt], 0, 0, 0);
            }
        }

        // ---- epilogue: branch-free fast gelu + dot(W2) + butterfly ----
#pragma unroll
        for (int r = 0; r < 4; ++r) {
            float s = 0.f;
#pragma unroll
            for (int nt = 0; nt < 4; ++nt)
                s = fmaf(gelu_fast(acc[nt][r]), w2v[nt], s);
#pragma unroll
            for (int off = 1; off < 16; off <<= 1) s += __shfl_xor(s, off);
            const int j = j0 + wave * 16 + kg * 4 + r;
            if (m == r && j <= i) p[j] = (s + b2v) * 0.125f;
        }
    }
    __syncthreads();   // p[0..i] complete

    // ---- softmax over p[0..i] ----
    const int n = i + 1;
    float mx = -1e30f;
    for (int jj = tid; jj < n; jj += 256) mx = fmaxf(mx, p[jj]);
#pragma unroll
    for (int off = 32; off > 0; off >>= 1) mx = fmaxf(mx, __shfl_down(mx, off));
    if (lane == 0) red[wave] = mx;
    __syncthreads();
    const float M = fmaxf(fmaxf(red[0], red[1]), fmaxf(red[2], red[3]));
    __syncthreads();

    float s = 0.f;
    for (int jj = tid; jj < n; jj += 256) {
        float e = __expf(p[jj] - M);
        p[jj] = e;
        s += e;
    }
#pragma unroll
    for (int off = 32; off > 0; off >>= 1) s += __shfl_down(s, off);
    if (lane == 0) red[wave] = s;
    __syncthreads();
    const float S = red[0] + red[1] + red[2] + red[3];
    const float inv = 1.f / S;

    // ---- PV: float4 per lane; wave covers 4 rows x 64 cols per iter ----
    const int c4 = lane & 15;
    const int jr = lane >> 4;
    const float4v* v4 = (const float4v*)(v + (size_t)b * TT * HH);
    float4v acc = {0.f, 0.f, 0.f, 0.f};
    for (int base = wave * 4; base < n; base += 16) {
        int j = base + jr;
        float pj = (j < n) ? p[j] : 0.f;
        int jc = (j < n) ? j : 0;            // clamp: avoid stray reads
        float4v vv = v4[jc * 16 + c4];
        acc += vv * pj;
    }
#pragma unroll
    for (int off = 16; off <= 32; off <<= 1) {
        float4v t;
        t[0] = __shfl_xor(acc[0], off);
        t[1] = __shfl_xor(acc[1], off);
        t[2] = __shfl_xor(acc[2], off);
        t[3] = __shfl_xor(acc[3], off);
        acc += t;
    }
    if (jr == 0) part[wave][c4] = acc;
    __syncthreads();
    if (tid < 16) {
        float4v r = (part[0][tid] + part[1][tid] + part[2][tid] + part[3][tid]) * inv;
        *((float4v*)(out + ((size_t)b * TT + i) * HH) + tid) = r;
    }
}

// ---------------------------------------------------------------------------
extern "C" void kernel_launch(void* const* d_in, const int* in_sizes, int n_in,
                              void* d_out, int out_size, void* d_ws, size_t ws_size,
                              hipStream_t stream)
{
    const float* x       = (const float*)d_in[0];
    const float* pos_emb = (const float*)d_in[1];
    const float* pd      = (const float*)d_in[2];
    const float* W1      = (const float*)d_in[3];
    const float* b1      = (const float*)d_in[4];
    const float* W2      = (const float*)d_in[5];
    const float* b2      = (const float*)d_in[6];
    const float* Wv      = (const float*)d_in[7];
    const float* bv      = (const float*)d_in[8];
    float* out = (float*)d_out;

    float* ws = (float*)d_ws;
    // layout (floats): Wpt [4096] | kp [65536] | qpb [65536] | v [65536]
    unsigned short* Wpt = (unsigned short*)ws;          // 8192 ushorts
    float* kp  = ws + 4096;
    float* qpb = ws + 4096 + 65536;
    float* v   = ws + 4096 + 131072;

    prep_kernel<<<dim3(BB * TT + 32), dim3(64), 0, stream>>>(x, pos_emb, W1, b1, Wv, bv, kp, qpb, v, Wpt);
    fused_kernel<<<dim3(TT, BB), dim3(256), 0, stream>>>(pd, Wpt, W2, b2, kp, qpb, v, out);
}